// Round 1
// baseline (343.783 us; speedup 1.0000x reference)
//
#include <hip/hip_runtime.h>
#include <stdint.h>

// C = binarize(X) @ binarize(W), exact via XNOR-popcount.
// X: 8192x4096 f32, W: 4096x4096 f32, C: 8192x4096 f32.
#define MDIM 8192
#define NDIM 4096
#define KDIM 4096
#define KW   (KDIM / 32)   // 128 packed words along K

// --- pack X (binarize rows, store transposed XpT[kw][i]) ---------------------
// One wave handles (row i, 64-wide k chunk kw2): coalesced 256B read + ballot.
__global__ __launch_bounds__(256) void pack_x_kernel(const float* __restrict__ X,
                                                     uint32_t* __restrict__ XpT) {
    int wid  = blockIdx.x * 4 + (threadIdx.x >> 6);   // global wave id
    int lane = threadIdx.x & 63;
    int i    = wid >> 6;          // row (64 chunks per row)
    int kw2  = wid & 63;          // which 64-wide k chunk
    float v = X[(size_t)i * KDIM + (size_t)kw2 * 64 + lane];
    unsigned long long m = __ballot(v >= 0.0f);       // bit l = lane l = k offset l
    if (lane == 0) {
        XpT[(size_t)(2 * kw2)     * MDIM + i] = (uint32_t)m;          // k bits 0..31
        XpT[(size_t)(2 * kw2 + 1) * MDIM + i] = (uint32_t)(m >> 32);  // k bits 32..63
    }
}

// --- pack W (binarize along k, store Wp[kw][j]) ------------------------------
// Thread per (kw, j); per t the 256 lanes read 1 KiB contiguous (coalesced).
__global__ __launch_bounds__(256) void pack_w_kernel(const float* __restrict__ W,
                                                     uint32_t* __restrict__ Wp) {
    int j  = blockIdx.x * 256 + threadIdx.x;
    int kw = blockIdx.y;
    uint32_t w = 0;
#pragma unroll
    for (int t = 0; t < 32; ++t) {
        float v = W[(size_t)(kw * 32 + t) * NDIM + j];
        w |= (v >= 0.0f ? 1u : 0u) << t;
    }
    Wp[(size_t)kw * NDIM + j] = w;
}

// --- main: 128x128 block tile, 8x8 register tile per thread ------------------
// C[i][j] = KDIM - 2 * sum_kw popc(Xp[i][kw] ^ Wp[kw][j])
__global__ __launch_bounds__(256) void binmm_kernel(const uint32_t* __restrict__ Wp,
                                                    const uint32_t* __restrict__ XpT,
                                                    float* __restrict__ C) {
    const int tx = threadIdx.x & 15;   // j sub-tile
    const int ty = threadIdx.x >> 4;   // i sub-tile
    const uint4* Wp4 = (const uint4*)Wp;    // row stride NDIM/4 = 1024 uint4
    const uint4* Xp4 = (const uint4*)XpT;   // row stride MDIM/4 = 2048 uint4

    uint32_t pc[8][8];
#pragma unroll
    for (int r = 0; r < 8; ++r)
#pragma unroll
        for (int c = 0; c < 8; ++c) pc[r][c] = 0;

    const int wbase = blockIdx.x * 32 + tx * 2;   // uint4 index in Wp row (j0/4)
    const int xbase = blockIdx.y * 32 + ty * 2;   // uint4 index in XpT row (i0/4)

    for (int kw = 0; kw < KW; ++kw) {
        uint4 wa = Wp4[(size_t)kw * 1024 + wbase];
        uint4 wb = Wp4[(size_t)kw * 1024 + wbase + 1];
        uint4 xa = Xp4[(size_t)kw * 2048 + xbase];
        uint4 xb = Xp4[(size_t)kw * 2048 + xbase + 1];
        uint32_t ww[8] = {wa.x, wa.y, wa.z, wa.w, wb.x, wb.y, wb.z, wb.w};
        uint32_t xw[8] = {xa.x, xa.y, xa.z, xa.w, xb.x, xb.y, xb.z, xb.w};
#pragma unroll
        for (int r = 0; r < 8; ++r)
#pragma unroll
            for (int c = 0; c < 8; ++c)
                pc[r][c] += __popc(xw[r] ^ ww[c]);   // v_xor_b32 + v_bcnt_u32_b32(acc)
    }

    const int i0 = blockIdx.y * 128 + ty * 8;
    const int j0 = blockIdx.x * 128 + tx * 8;
#pragma unroll
    for (int r = 0; r < 8; ++r) {
        float4 o0, o1;
        o0.x = (float)(KDIM - 2 * (int)pc[r][0]);
        o0.y = (float)(KDIM - 2 * (int)pc[r][1]);
        o0.z = (float)(KDIM - 2 * (int)pc[r][2]);
        o0.w = (float)(KDIM - 2 * (int)pc[r][3]);
        o1.x = (float)(KDIM - 2 * (int)pc[r][4]);
        o1.y = (float)(KDIM - 2 * (int)pc[r][5]);
        o1.z = (float)(KDIM - 2 * (int)pc[r][6]);
        o1.w = (float)(KDIM - 2 * (int)pc[r][7]);
        *(float4*)&C[(size_t)(i0 + r) * NDIM + j0]     = o0;
        *(float4*)&C[(size_t)(i0 + r) * NDIM + j0 + 4] = o1;
    }
}

extern "C" void kernel_launch(void* const* d_in, const int* in_sizes, int n_in,
                              void* d_out, int out_size, void* d_ws, size_t ws_size,
                              hipStream_t stream) {
    const float* x = (const float*)d_in[0];   // [8192][4096]
    const float* w = (const float*)d_in[1];   // [4096][4096]
    float* out = (float*)d_out;               // [8192][4096]

    // workspace layout: Wp [KW][NDIM] u32 (2 MiB) then XpT [KW][MDIM] u32 (4 MiB)
    uint32_t* Wp  = (uint32_t*)d_ws;
    uint32_t* XpT = (uint32_t*)((char*)d_ws + (size_t)KW * NDIM * sizeof(uint32_t));

    pack_w_kernel<<<dim3(NDIM / 256, KW), 256, 0, stream>>>(w, Wp);
    pack_x_kernel<<<(MDIM * (KDIM / 64)) / 4, 256, 0, stream>>>(x, XpT);
    binmm_kernel<<<dim3(NDIM / 128, MDIM / 128), 256, 0, stream>>>(Wp, XpT, out);
}

// Round 2
// 336.806 us; speedup vs baseline: 1.0207x; 1.0207x over previous
//
#include <hip/hip_runtime.h>
#include <stdint.h>

// C = binarize(X) @ binarize(W), exact via XNOR-popcount.
// X: 8192x4096 f32, W: 4096x4096 f32, C: 8192x4096 f32.
#define MDIM 8192
#define NDIM 4096
#define KDIM 4096
#define KW   (KDIM / 32)   // 128 packed words along K

// --- pack X (binarize rows, store transposed XpT[kw][i]) ---------------------
__global__ __launch_bounds__(256) void pack_x_kernel(const float* __restrict__ X,
                                                     uint32_t* __restrict__ XpT) {
    int wid  = blockIdx.x * 4 + (threadIdx.x >> 6);   // global wave id
    int lane = threadIdx.x & 63;
    int i    = wid >> 6;          // row (64 chunks per row)
    int kw2  = wid & 63;          // which 64-wide k chunk
    float v = X[(size_t)i * KDIM + (size_t)kw2 * 64 + lane];
    unsigned long long m = __ballot(v >= 0.0f);       // bit l = lane l = k offset l
    if (lane == 0) {
        XpT[(size_t)(2 * kw2)     * MDIM + i] = (uint32_t)m;          // k bits 0..31
        XpT[(size_t)(2 * kw2 + 1) * MDIM + i] = (uint32_t)(m >> 32);  // k bits 32..63
    }
}

// --- pack W (binarize along k, store Wp[kw][j]) ------------------------------
__global__ __launch_bounds__(256) void pack_w_kernel(const float* __restrict__ W,
                                                     uint32_t* __restrict__ Wp) {
    int j  = blockIdx.x * 256 + threadIdx.x;
    int kw = blockIdx.y;
    uint32_t w = 0;
#pragma unroll
    for (int t = 0; t < 32; ++t) {
        float v = W[(size_t)(kw * 32 + t) * NDIM + j];
        w |= (v >= 0.0f ? 1u : 0u) << t;
    }
    Wp[(size_t)kw * NDIM + j] = w;
}

// --- main: 128x128 block tile, 8x8 register tile per thread ------------------
// pc[r][c] += popc(x ^ w) via v_bcnt_u32_b32's fused add (exactly 2 VALU/word).
#define BCNT_ACC(dst, t) asm("v_bcnt_u32_b32 %0, %1, %0" : "+v"(dst) : "v"(t))

#define ROW8(xv, r, W0, W1, W2, W3, W4, W5, W6, W7) do {            \
        uint32_t t_;                                                 \
        t_ = (xv) ^ (W0); BCNT_ACC(pc[r][0], t_);                    \
        t_ = (xv) ^ (W1); BCNT_ACC(pc[r][1], t_);                    \
        t_ = (xv) ^ (W2); BCNT_ACC(pc[r][2], t_);                    \
        t_ = (xv) ^ (W3); BCNT_ACC(pc[r][3], t_);                    \
        t_ = (xv) ^ (W4); BCNT_ACC(pc[r][4], t_);                    \
        t_ = (xv) ^ (W5); BCNT_ACC(pc[r][5], t_);                    \
        t_ = (xv) ^ (W6); BCNT_ACC(pc[r][6], t_);                    \
        t_ = (xv) ^ (W7); BCNT_ACC(pc[r][7], t_);                    \
    } while (0)

#define TILE64(wa, wb, xa, xb) do {                                              \
        ROW8(xa.x, 0, wa.x, wa.y, wa.z, wa.w, wb.x, wb.y, wb.z, wb.w);           \
        ROW8(xa.y, 1, wa.x, wa.y, wa.z, wa.w, wb.x, wb.y, wb.z, wb.w);           \
        ROW8(xa.z, 2, wa.x, wa.y, wa.z, wa.w, wb.x, wb.y, wb.z, wb.w);           \
        ROW8(xa.w, 3, wa.x, wa.y, wa.z, wa.w, wb.x, wb.y, wb.z, wb.w);           \
        ROW8(xb.x, 4, wa.x, wa.y, wa.z, wa.w, wb.x, wb.y, wb.z, wb.w);           \
        ROW8(xb.y, 5, wa.x, wa.y, wa.z, wa.w, wb.x, wb.y, wb.z, wb.w);           \
        ROW8(xb.z, 6, wa.x, wa.y, wa.z, wa.w, wb.x, wb.y, wb.z, wb.w);           \
        ROW8(xb.w, 7, wa.x, wa.y, wa.z, wa.w, wb.x, wb.y, wb.z, wb.w);           \
    } while (0)

__global__ __launch_bounds__(256) void binmm_kernel(const uint32_t* __restrict__ Wp,
                                                    const uint32_t* __restrict__ XpT,
                                                    float* __restrict__ C) {
    const int tx = threadIdx.x & 15;   // j sub-tile
    const int ty = threadIdx.x >> 4;   // i sub-tile

    uint32_t pc[8][8];
#pragma unroll
    for (int r = 0; r < 8; ++r)
#pragma unroll
        for (int c = 0; c < 8; ++c) pc[r][c] = 0;

    // pointer-increment addressing (no per-iter 64-bit multiplies)
    const uint4* wptr = (const uint4*)Wp  + blockIdx.x * 32 + tx * 2;  // row stride 1024 uint4
    const uint4* xptr = (const uint4*)XpT + blockIdx.y * 32 + ty * 2;  // row stride 2048 uint4

    for (int kw = 0; kw < KW; kw += 2) {
        uint4 wa0 = wptr[0],    wb0 = wptr[1];
        uint4 xa0 = xptr[0],    xb0 = xptr[1];
        uint4 wa1 = wptr[1024], wb1 = wptr[1025];
        uint4 xa1 = xptr[2048], xb1 = xptr[2049];
        wptr += 2048;
        xptr += 4096;
        TILE64(wa0, wb0, xa0, xb0);
        TILE64(wa1, wb1, xa1, xb1);
    }

    const int i0 = blockIdx.y * 128 + ty * 8;
    const int j0 = blockIdx.x * 128 + tx * 8;
#pragma unroll
    for (int r = 0; r < 8; ++r) {
        float4 o0, o1;
        o0.x = (float)(KDIM - 2 * (int)pc[r][0]);
        o0.y = (float)(KDIM - 2 * (int)pc[r][1]);
        o0.z = (float)(KDIM - 2 * (int)pc[r][2]);
        o0.w = (float)(KDIM - 2 * (int)pc[r][3]);
        o1.x = (float)(KDIM - 2 * (int)pc[r][4]);
        o1.y = (float)(KDIM - 2 * (int)pc[r][5]);
        o1.z = (float)(KDIM - 2 * (int)pc[r][6]);
        o1.w = (float)(KDIM - 2 * (int)pc[r][7]);
        *(float4*)&C[(size_t)(i0 + r) * NDIM + j0]     = o0;
        *(float4*)&C[(size_t)(i0 + r) * NDIM + j0 + 4] = o1;
    }
}

extern "C" void kernel_launch(void* const* d_in, const int* in_sizes, int n_in,
                              void* d_out, int out_size, void* d_ws, size_t ws_size,
                              hipStream_t stream) {
    const float* x = (const float*)d_in[0];   // [8192][4096]
    const float* w = (const float*)d_in[1];   // [4096][4096]
    float* out = (float*)d_out;               // [8192][4096]

    // workspace layout: Wp [KW][NDIM] u32 (2 MiB) then XpT [KW][MDIM] u32 (4 MiB)
    uint32_t* Wp  = (uint32_t*)d_ws;
    uint32_t* XpT = (uint32_t*)((char*)d_ws + (size_t)KW * NDIM * sizeof(uint32_t));

    pack_w_kernel<<<dim3(NDIM / 256, KW), 256, 0, stream>>>(w, Wp);
    pack_x_kernel<<<(MDIM * (KDIM / 64)) / 4, 256, 0, stream>>>(x, XpT);
    binmm_kernel<<<dim3(NDIM / 128, MDIM / 128), 256, 0, stream>>>(Wp, XpT, out);
}

// Round 3
// 218.515 us; speedup vs baseline: 1.5733x; 1.5413x over previous
//
#include <hip/hip_runtime.h>
#include <stdint.h>

// C = binarize(X) @ binarize(W), exact via int8 +-1 MFMA.
// X: 8192x4096 f32, W: 4096x4096 f32, C: 8192x4096 f32.
#define MDIM 8192
#define NDIM 4096
#define KDIM 4096

typedef __attribute__((ext_vector_type(4)))  int i32x4;
typedef __attribute__((ext_vector_type(16))) int i32x16;

__device__ __forceinline__ void gload16(const void* g, void* l) {
    __builtin_amdgcn_global_load_lds(
        (const __attribute__((address_space(1))) void*)g,
        (__attribute__((address_space(3))) void*)l, 16, 0, 0);
}

// ---------------- pack X -> Ai8 [M][K] sign(+1/-1) int8 ----------------------
__global__ __launch_bounds__(256) void pack_a_kernel(const float* __restrict__ X,
                                                     uint8_t* __restrict__ A) {
    int gt = blockIdx.x * 256 + threadIdx.x;          // 16 elements per thread
    const float4* x4 = (const float4*)X + (size_t)gt * 4;
    uint32_t w[4];
#pragma unroll
    for (int q = 0; q < 4; ++q) {
        float4 v = x4[q];
        uint32_t b0 = (v.x >= 0.f) ? 0x01u : 0xFFu;
        uint32_t b1 = (v.y >= 0.f) ? 0x01u : 0xFFu;
        uint32_t b2 = (v.z >= 0.f) ? 0x01u : 0xFFu;
        uint32_t b3 = (v.w >= 0.f) ? 0x01u : 0xFFu;
        w[q] = b0 | (b1 << 8) | (b2 << 16) | (b3 << 24);
    }
    ((uint4*)A)[gt] = make_uint4(w[0], w[1], w[2], w[3]);
}

// ---------------- pack W -> BT [N][K] sign int8, transposed ------------------
// 64x64 tile transpose through LDS.
__global__ __launch_bounds__(256) void pack_bt_kernel(const float* __restrict__ W,
                                                      uint8_t* __restrict__ BT) {
    __shared__ uint8_t t[64][72];                     // +8 pad
    const int tid = threadIdx.x;
    const int k0 = blockIdx.y * 64, n0 = blockIdx.x * 64;
#pragma unroll
    for (int r = 0; r < 4; ++r) {
        int e  = r * 1024 + tid * 4;                  // element in 64x64 tile
        int k  = e >> 6;
        int nn = e & 63;
        float4 v = *(const float4*)&W[(size_t)(k0 + k) * NDIM + n0 + nn];
        uint32_t b0 = (v.x >= 0.f) ? 0x01u : 0xFFu;
        uint32_t b1 = (v.y >= 0.f) ? 0x01u : 0xFFu;
        uint32_t b2 = (v.z >= 0.f) ? 0x01u : 0xFFu;
        uint32_t b3 = (v.w >= 0.f) ? 0x01u : 0xFFu;
        *(uint32_t*)&t[k][nn] = b0 | (b1 << 8) | (b2 << 16) | (b3 << 24);
    }
    __syncthreads();
    const int n = tid >> 2, kc = tid & 3;
    uint32_t w[4];
#pragma unroll
    for (int q = 0; q < 4; ++q) {
        int kk = kc * 16 + q * 4;
        w[q] = (uint32_t)t[kk][n] | ((uint32_t)t[kk + 1][n] << 8) |
               ((uint32_t)t[kk + 2][n] << 16) | ((uint32_t)t[kk + 3][n] << 24);
    }
    *(uint4*)&BT[(size_t)(n0 + n) * KDIM + k0 + kc * 16] = make_uint4(w[0], w[1], w[2], w[3]);
}

// ---------------- main: i8 MFMA GEMM, 128x128 tile, BK=64 --------------------
// 4 waves (2x2), each computes 64x64 via 2x2 mfma_i32_32x32x32_i8 frags.
// LDS linear [128][64]B; bank-conflict fix: 16B slots XOR-swizzled via
// pre-swizzled GLOBAL source (global_load_lds dest must stay linear, G21).
#define MFMA_I8(a, b, c) __builtin_amdgcn_mfma_i32_32x32x32_i8((a), (b), (c), 0, 0, 0)

__global__ __launch_bounds__(256) void binmm_i8_kernel(const uint8_t* __restrict__ A,
                                                       const uint8_t* __restrict__ BT,
                                                       float* __restrict__ C) {
    __shared__ i32x4 AsV[512];                        // 8 KiB: A tile [128][64]B
    __shared__ i32x4 BsV[512];                        // 8 KiB: B tile [128][64]B
    uint8_t* As = (uint8_t*)AsV;
    uint8_t* Bs = (uint8_t*)BsV;

    const int tid  = threadIdx.x;
    const int lane = tid & 63, wid = tid >> 6;
    const int wr = wid >> 1, wc = wid & 1;            // wave tile (2x2 of 64x64)
    const int r5 = lane & 31, hi = lane >> 5;
    const int fr = (r5 >> 2) & 3;                     // read-side swizzle key

    // --- staging setup: 2 A-loads + 2 B-loads of 16B per thread per K-step ---
    const int srow = tid >> 2;                        // 0..63
    const int g    = (tid & 3) ^ ((tid >> 4) & 3);    // inverse-swizzled src slot
    const int m0 = blockIdx.y * 128, n0 = blockIdx.x * 128;
    const uint8_t* srcA0 = A  + (size_t)(m0 + srow)      * KDIM + g * 16;
    const uint8_t* srcA1 = A  + (size_t)(m0 + 64 + srow) * KDIM + g * 16;
    const uint8_t* srcB0 = BT + (size_t)(n0 + srow)      * KDIM + g * 16;
    const uint8_t* srcB1 = BT + (size_t)(n0 + 64 + srow) * KDIM + g * 16;
    uint8_t* dA0 = As + tid * 16;                     // linear, lane-contiguous
    uint8_t* dA1 = As + 4096 + tid * 16;
    uint8_t* dB0 = Bs + tid * 16;
    uint8_t* dB1 = Bs + 4096 + tid * 16;

    // --- fragment read offsets (swizzled) ---
    int offA0[2], offA1[2], offB0[2], offB1[2];
#pragma unroll
    for (int s = 0; s < 2; ++s) {
        int sw = ((s * 2 + hi) ^ fr) * 16;            // 16B slot after swizzle
        offA0[s] = (wr * 64 + r5)      * 64 + sw;
        offA1[s] = (wr * 64 + 32 + r5) * 64 + sw;
        offB0[s] = (wc * 64 + r5)      * 64 + sw;
        offB1[s] = (wc * 64 + 32 + r5) * 64 + sw;
    }

    i32x16 acc00 = {0,0,0,0,0,0,0,0,0,0,0,0,0,0,0,0};
    i32x16 acc01 = {0,0,0,0,0,0,0,0,0,0,0,0,0,0,0,0};
    i32x16 acc10 = {0,0,0,0,0,0,0,0,0,0,0,0,0,0,0,0};
    i32x16 acc11 = {0,0,0,0,0,0,0,0,0,0,0,0,0,0,0,0};

    for (int t = 0; t < KDIM / 64; ++t) {
        gload16(srcA0, dA0);
        gload16(srcA1, dA1);
        gload16(srcB0, dB0);
        gload16(srcB1, dB1);
        srcA0 += 64; srcA1 += 64; srcB0 += 64; srcB1 += 64;
        __syncthreads();                              // drains vmcnt (m97 pattern)
#pragma unroll
        for (int s = 0; s < 2; ++s) {
            i32x4 a0 = *(const i32x4*)(As + offA0[s]);
            i32x4 a1 = *(const i32x4*)(As + offA1[s]);
            i32x4 b0 = *(const i32x4*)(Bs + offB0[s]);
            i32x4 b1 = *(const i32x4*)(Bs + offB1[s]);
            acc00 = MFMA_I8(a0, b0, acc00);
            acc01 = MFMA_I8(a0, b1, acc01);
            acc10 = MFMA_I8(a1, b0, acc10);
            acc11 = MFMA_I8(a1, b1, acc11);
        }
        __syncthreads();                              // before next overwrite
    }

    // --- epilogue: C/D layout (32x32): col = lane&31, row = (reg&3)+8*(reg>>2)+4*hi
    const int mBase = m0 + wr * 64;
    const size_t nIdx = (size_t)(n0 + wc * 64 + r5);
#pragma unroll
    for (int reg = 0; reg < 16; ++reg) {
        int rr = (reg & 3) + 8 * (reg >> 2) + 4 * hi;
        C[(size_t)(mBase + rr)      * NDIM + nIdx]      = (float)acc00[reg];
        C[(size_t)(mBase + rr)      * NDIM + nIdx + 32] = (float)acc01[reg];
        C[(size_t)(mBase + 32 + rr) * NDIM + nIdx]      = (float)acc10[reg];
        C[(size_t)(mBase + 32 + rr) * NDIM + nIdx + 32] = (float)acc11[reg];
    }
}

// ======================= fallback: R1 bcnt path ==============================
#define KW (KDIM / 32)

__global__ __launch_bounds__(256) void pack_x_kernel(const float* __restrict__ X,
                                                     uint32_t* __restrict__ XpT) {
    int wid  = blockIdx.x * 4 + (threadIdx.x >> 6);
    int lane = threadIdx.x & 63;
    int i    = wid >> 6;
    int kw2  = wid & 63;
    float v = X[(size_t)i * KDIM + (size_t)kw2 * 64 + lane];
    unsigned long long m = __ballot(v >= 0.0f);
    if (lane == 0) {
        XpT[(size_t)(2 * kw2)     * MDIM + i] = (uint32_t)m;
        XpT[(size_t)(2 * kw2 + 1) * MDIM + i] = (uint32_t)(m >> 32);
    }
}

__global__ __launch_bounds__(256) void pack_w_kernel(const float* __restrict__ W,
                                                     uint32_t* __restrict__ Wp) {
    int j  = blockIdx.x * 256 + threadIdx.x;
    int kw = blockIdx.y;
    uint32_t w = 0;
#pragma unroll
    for (int t = 0; t < 32; ++t) {
        float v = W[(size_t)(kw * 32 + t) * NDIM + j];
        w |= (v >= 0.0f ? 1u : 0u) << t;
    }
    Wp[(size_t)kw * NDIM + j] = w;
}

#define BCNT_ACC(dst, t) asm("v_bcnt_u32_b32 %0, %1, %0" : "+v"(dst) : "v"(t))
#define ROW8(xv, r, W0, W1, W2, W3, W4, W5, W6, W7) do {            \
        uint32_t t_;                                                 \
        t_ = (xv) ^ (W0); BCNT_ACC(pc[r][0], t_);                    \
        t_ = (xv) ^ (W1); BCNT_ACC(pc[r][1], t_);                    \
        t_ = (xv) ^ (W2); BCNT_ACC(pc[r][2], t_);                    \
        t_ = (xv) ^ (W3); BCNT_ACC(pc[r][3], t_);                    \
        t_ = (xv) ^ (W4); BCNT_ACC(pc[r][4], t_);                    \
        t_ = (xv) ^ (W5); BCNT_ACC(pc[r][5], t_);                    \
        t_ = (xv) ^ (W6); BCNT_ACC(pc[r][6], t_);                    \
        t_ = (xv) ^ (W7); BCNT_ACC(pc[r][7], t_);                    \
    } while (0)
#define TILE64(wa, wb, xa, xb) do {                                              \
        ROW8(xa.x, 0, wa.x, wa.y, wa.z, wa.w, wb.x, wb.y, wb.z, wb.w);           \
        ROW8(xa.y, 1, wa.x, wa.y, wa.z, wa.w, wb.x, wb.y, wb.z, wb.w);           \
        ROW8(xa.z, 2, wa.x, wa.y, wa.z, wa.w, wb.x, wb.y, wb.z, wb.w);           \
        ROW8(xa.w, 3, wa.x, wa.y, wa.z, wa.w, wb.x, wb.y, wb.z, wb.w);           \
        ROW8(xb.x, 4, wa.x, wa.y, wa.z, wa.w, wb.x, wb.y, wb.z, wb.w);           \
        ROW8(xb.y, 5, wa.x, wa.y, wa.z, wa.w, wb.x, wb.y, wb.z, wb.w);           \
        ROW8(xb.z, 6, wa.x, wa.y, wa.z, wa.w, wb.x, wb.y, wb.z, wb.w);           \
        ROW8(xb.w, 7, wa.x, wa.y, wa.z, wa.w, wb.x, wb.y, wb.z, wb.w);           \
    } while (0)

__global__ __launch_bounds__(256) void binmm_kernel(const uint32_t* __restrict__ Wp,
                                                    const uint32_t* __restrict__ XpT,
                                                    float* __restrict__ C) {
    const int tx = threadIdx.x & 15;
    const int ty = threadIdx.x >> 4;
    uint32_t pc[8][8];
#pragma unroll
    for (int r = 0; r < 8; ++r)
#pragma unroll
        for (int c = 0; c < 8; ++c) pc[r][c] = 0;
    const uint4* wptr = (const uint4*)Wp  + blockIdx.x * 32 + tx * 2;
    const uint4* xptr = (const uint4*)XpT + blockIdx.y * 32 + ty * 2;
    for (int kw = 0; kw < KW; kw += 2) {
        uint4 wa0 = wptr[0],    wb0 = wptr[1];
        uint4 xa0 = xptr[0],    xb0 = xptr[1];
        uint4 wa1 = wptr[1024], wb1 = wptr[1025];
        uint4 xa1 = xptr[2048], xb1 = xptr[2049];
        wptr += 2048;
        xptr += 4096;
        TILE64(wa0, wb0, xa0, xb0);
        TILE64(wa1, wb1, xa1, xb1);
    }
    const int i0 = blockIdx.y * 128 + ty * 8;
    const int j0 = blockIdx.x * 128 + tx * 8;
#pragma unroll
    for (int r = 0; r < 8; ++r) {
        float4 o0, o1;
        o0.x = (float)(KDIM - 2 * (int)pc[r][0]);
        o0.y = (float)(KDIM - 2 * (int)pc[r][1]);
        o0.z = (float)(KDIM - 2 * (int)pc[r][2]);
        o0.w = (float)(KDIM - 2 * (int)pc[r][3]);
        o1.x = (float)(KDIM - 2 * (int)pc[r][4]);
        o1.y = (float)(KDIM - 2 * (int)pc[r][5]);
        o1.z = (float)(KDIM - 2 * (int)pc[r][6]);
        o1.w = (float)(KDIM - 2 * (int)pc[r][7]);
        *(float4*)&C[(size_t)(i0 + r) * NDIM + j0]     = o0;
        *(float4*)&C[(size_t)(i0 + r) * NDIM + j0 + 4] = o1;
    }
}

// =============================================================================
extern "C" void kernel_launch(void* const* d_in, const int* in_sizes, int n_in,
                              void* d_out, int out_size, void* d_ws, size_t ws_size,
                              hipStream_t stream) {
    const float* x = (const float*)d_in[0];   // [8192][4096]
    const float* w = (const float*)d_in[1];   // [4096][4096]
    float* out = (float*)d_out;               // [8192][4096]

    const size_t needA = (size_t)MDIM * KDIM;          // 32 MiB i8
    const size_t needB = (size_t)NDIM * KDIM;          // 16 MiB i8
    if (ws_size >= needA + needB) {
        uint8_t* Ai8 = (uint8_t*)d_ws;
        uint8_t* BTi = (uint8_t*)d_ws + needA;
        pack_a_kernel<<<(MDIM * KDIM / 16) / 256, 256, 0, stream>>>(x, Ai8);
        pack_bt_kernel<<<dim3(NDIM / 64, KDIM / 64), 256, 0, stream>>>(w, BTi);
        binmm_i8_kernel<<<dim3(NDIM / 128, MDIM / 128), 256, 0, stream>>>(Ai8, BTi, out);
    } else {
        uint32_t* Wp  = (uint32_t*)d_ws;
        uint32_t* XpT = (uint32_t*)((char*)d_ws + (size_t)KW * NDIM * sizeof(uint32_t));
        pack_w_kernel<<<dim3(NDIM / 256, KW), 256, 0, stream>>>(w, Wp);
        pack_x_kernel<<<(MDIM * (KDIM / 64)) / 4, 256, 0, stream>>>(x, XpT);
        binmm_kernel<<<dim3(NDIM / 128, MDIM / 128), 256, 0, stream>>>(Wp, XpT, out);
    }
}

// Round 4
// 132.325 us; speedup vs baseline: 2.5980x; 1.6513x over previous
//
#include <hip/hip_runtime.h>
#include <stdint.h>

// C = binarize(X) @ binarize(W), exact via MX-fp4 (+-1) scaled MFMA.
// X: 8192x4096 f32, W: 4096x4096 f32, C: 8192x4096 f32.
// fp4 e2m1: +1.0 = 0x2, -1.0 = 0xA. Scale E8M0 127 = 1.0 (word 0x7F7F7F7F).
#define MDIM 8192
#define NDIM 4096
#define KDIM 4096
#define KB2  (KDIM / 2)     // 2048 bytes per packed row (2 fp4/byte)
#define BKB  128            // K-tile bytes = 256 fp4 elems
#define NKT  (KDIM / 256)   // 16 K-tiles

typedef __attribute__((ext_vector_type(4))) int   i32x4;
typedef __attribute__((ext_vector_type(8))) int   i32x8;
typedef __attribute__((ext_vector_type(4))) float f32x4;

__device__ __forceinline__ void gload16(const void* g, void* l) {
    __builtin_amdgcn_global_load_lds(
        (const __attribute__((address_space(1))) void*)g,
        (__attribute__((address_space(3))) void*)l, 16, 0, 0);
}

__device__ __forceinline__ i32x8 pad8(i32x4 v) {
    i32x8 r;
    r[0] = v[0]; r[1] = v[1]; r[2] = v[2]; r[3] = v[3];
    r[4] = 0;    r[5] = 0;    r[6] = 0;    r[7] = 0;
    return r;
}

// scale 1.0 everywhere; fp4 format code = 4 for both operands.
#define MFMA_FP4(a, b, c)                                                   \
    __builtin_amdgcn_mfma_scale_f32_16x16x128_f8f6f4(                        \
        (a), (b), (c), 4, 4, 0, 0x7F7F7F7F, 0, 0x7F7F7F7F)

// ---------------- pack X -> A4 [M][K/2] fp4 nibbles --------------------------
// thread: 16 f32 -> 8 bytes. low nibble = even k (A and B identical convention,
// so any HW-internal K-permutation cancels in the dot product).
__global__ __launch_bounds__(256) void pack_a4_kernel(const float* __restrict__ X,
                                                      uint8_t* __restrict__ A4) {
    size_t gt = (size_t)blockIdx.x * 256 + threadIdx.x;
    const float4* x4 = (const float4*)X + gt * 4;
    uint32_t out[2] = {0, 0};
#pragma unroll
    for (int q = 0; q < 4; ++q) {
        float4 v = x4[q];
        uint32_t b0 = (v.x >= 0.f ? 0x2u : 0xAu) | ((v.y >= 0.f ? 0x2u : 0xAu) << 4);
        uint32_t b1 = (v.z >= 0.f ? 0x2u : 0xAu) | ((v.w >= 0.f ? 0x2u : 0xAu) << 4);
        out[q >> 1] |= (b0 | (b1 << 8)) << ((q & 1) * 16);
    }
    ((uint2*)A4)[gt] = make_uint2(out[0], out[1]);
}

// ---------------- pack W -> B4T [N][K/2] fp4 nibbles, transposed -------------
__global__ __launch_bounds__(256) void pack_b4t_kernel(const float* __restrict__ W,
                                                       uint8_t* __restrict__ B4) {
    __shared__ uint8_t t[64][72];                 // sign nibbles, +8 pad
    const int tid = threadIdx.x;
    const int k0 = blockIdx.y * 64, n0 = blockIdx.x * 64;
#pragma unroll
    for (int r = 0; r < 4; ++r) {
        int e  = r * 1024 + tid * 4;
        int k  = e >> 6;
        int nn = e & 63;
        float4 v = *(const float4*)&W[(size_t)(k0 + k) * NDIM + n0 + nn];
        uint32_t b0 = (v.x >= 0.f) ? 0x2u : 0xAu;
        uint32_t b1 = (v.y >= 0.f) ? 0x2u : 0xAu;
        uint32_t b2 = (v.z >= 0.f) ? 0x2u : 0xAu;
        uint32_t b3 = (v.w >= 0.f) ? 0x2u : 0xAu;
        *(uint32_t*)&t[k][nn] = b0 | (b1 << 8) | (b2 << 16) | (b3 << 24);
    }
    __syncthreads();
    const int n = tid >> 2, kc = tid & 3;         // 16 k-elems -> 8 bytes each
    uint32_t w[2] = {0, 0};
#pragma unroll
    for (int b = 0; b < 8; ++b) {
        int k = kc * 16 + b * 2;
        uint32_t byte = (uint32_t)t[k][n] | ((uint32_t)t[k + 1][n] << 4);
        w[b >> 2] |= byte << ((b & 3) * 8);
    }
    *(uint2*)&B4[(size_t)(n0 + n) * KB2 + k0 / 2 + kc * 8] = make_uint2(w[0], w[1]);
}

// ---------------- main: fp4 MFMA GEMM, 128x128 tile, BK=256 elems ------------
// 4 waves (2x2), each 64x64 out = 4x4 frags of 16x16; 2 MFMA-K-steps per tile.
// LDS [128 rows][128 B], slot swizzle phys = logical ^ (row&7) applied on the
// pre-swizzled GLOBAL source (linear gload_lds dest) and on the ds_read side.
__global__ __launch_bounds__(256) void binmm_fp4_kernel(const uint8_t* __restrict__ A4,
                                                        const uint8_t* __restrict__ B4,
                                                        float* __restrict__ C) {
    __shared__ uint8_t As[128 * 128];             // 16 KiB
    __shared__ uint8_t Bs[128 * 128];             // 16 KiB

    const int tid = threadIdx.x, lane = tid & 63, wid = tid >> 6;
    const int wr = wid >> 1, wc = wid & 1;        // wave tile (2x2 of 64x64)
    const int l15 = lane & 15, g = lane >> 4;
    const int m0 = blockIdx.y * 128, n0 = blockIdx.x * 128;

    // staging: 4 chunks of 32 rows each for A and B; 16B per thread per chunk
    const int srow  = tid >> 3;                   // 0..31
    const int sslot = tid & 7;
    const uint8_t* gA[4];
    const uint8_t* gB[4];
    uint8_t* dA[4];
    uint8_t* dB[4];
#pragma unroll
    for (int p = 0; p < 4; ++p) {
        int row = srow + p * 32;
        int ss  = (sslot ^ (row & 7)) * 16;       // inverse-swizzled source slot
        gA[p] = A4 + (size_t)(m0 + row) * KB2 + ss;
        gB[p] = B4 + (size_t)(n0 + row) * KB2 + ss;
        dA[p] = As + p * 4096 + tid * 16;         // linear, lane-contiguous
        dB[p] = Bs + p * 4096 + tid * 16;
    }

    f32x4 acc[4][4];
#pragma unroll
    for (int m = 0; m < 4; ++m)
#pragma unroll
        for (int n = 0; n < 4; ++n) acc[m][n] = (f32x4){0.f, 0.f, 0.f, 0.f};

    for (int kt = 0; kt < NKT; ++kt) {
#pragma unroll
        for (int p = 0; p < 4; ++p) {
            gload16(gA[p], dA[p]);
            gload16(gB[p], dB[p]);
            gA[p] += BKB;
            gB[p] += BKB;
        }
        __syncthreads();                          // drains vmcnt (m97 pattern)
#pragma unroll
        for (int s = 0; s < 2; ++s) {             // two K=128 MFMA steps
            i32x8 af[4], bf[4];
#pragma unroll
            for (int m = 0; m < 4; ++m) {
                int row  = wr * 64 + m * 16 + l15;
                int slot = ((s * 4 + g) ^ (row & 7)) * 16;
                af[m] = pad8(*(const i32x4*)(As + row * 128 + slot));
            }
#pragma unroll
            for (int n = 0; n < 4; ++n) {
                int row  = wc * 64 + n * 16 + l15;
                int slot = ((s * 4 + g) ^ (row & 7)) * 16;
                bf[n] = pad8(*(const i32x4*)(Bs + row * 128 + slot));
            }
#pragma unroll
            for (int m = 0; m < 4; ++m)
#pragma unroll
                for (int n = 0; n < 4; ++n)
                    acc[m][n] = MFMA_FP4(af[m], bf[n], acc[m][n]);
        }
        __syncthreads();                          // before next overwrite
    }

    // epilogue: C/D 16x16 layout: col = lane&15, row = (lane>>4)*4 + reg
#pragma unroll
    for (int m = 0; m < 4; ++m) {
#pragma unroll
        for (int n = 0; n < 4; ++n) {
            size_t cc = (size_t)(n0 + wc * 64 + n * 16 + l15);
            int rbase = m0 + wr * 64 + m * 16 + g * 4;
#pragma unroll
            for (int reg = 0; reg < 4; ++reg)
                C[(size_t)(rbase + reg) * NDIM + cc] = acc[m][n][reg];
        }
    }
}

// =============================================================================
extern "C" void kernel_launch(void* const* d_in, const int* in_sizes, int n_in,
                              void* d_out, int out_size, void* d_ws, size_t ws_size,
                              hipStream_t stream) {
    const float* x = (const float*)d_in[0];   // [8192][4096]
    const float* w = (const float*)d_in[1];   // [4096][4096]
    float* out = (float*)d_out;               // [8192][4096]

    // workspace: A4 [M][K/2] (16 MiB) then B4T [N][K/2] (8 MiB)
    uint8_t* A4 = (uint8_t*)d_ws;
    uint8_t* B4 = (uint8_t*)d_ws + (size_t)MDIM * KB2;

    pack_a4_kernel<<<(int)((size_t)MDIM * KDIM / 16 / 256), 256, 0, stream>>>(x, A4);
    pack_b4t_kernel<<<dim3(NDIM / 64, KDIM / 64), 256, 0, stream>>>(w, B4);
    binmm_fp4_kernel<<<dim3(NDIM / 128, MDIM / 128), 256, 0, stream>>>(A4, B4, out);
}

// Round 5
// 124.820 us; speedup vs baseline: 2.7542x; 1.0601x over previous
//
#include <hip/hip_runtime.h>
#include <stdint.h>

// C = binarize(X) @ binarize(W), exact via MX-fp4 (+-1) scaled MFMA.
// X: 8192x4096 f32, W: 4096x4096 f32, C: 8192x4096 f32.
// fp4 e2m1: +1.0 = 0x2, -1.0 = 0xA. Scale E8M0 127 = 1.0 (word 0x7F7F7F7F).
//
// R5: 256x256 tile, 8 waves (2x4), BK=256 fp4 (128 B/row), double-buffered
// LDS (128 KiB) with ONE barrier per K-tile: stage(next) issued BEFORE the
// MFMA phase so the vmcnt drain at the barrier is covered by ~2850 cyc of
// MFMA (T3 "minimum 2-phase" recipe). Swizzle scheme carried from R4
// (verified conflict-free): phys_slot = logical_slot ^ (row&7), applied on
// the pre-swizzled GLOBAL source (linear gload_lds dest, G21) and on reads.
#define MDIM 8192
#define NDIM 4096
#define KDIM 4096
#define KB2  (KDIM / 2)     // 2048 B per packed row (2 fp4/byte)
#define BKB  128            // K-tile bytes = 256 fp4 elems
#define NKT  (KDIM / 256)   // 16 K-tiles

#define BM 256
#define BN 256
#define ABUF      32768     // A region per buffer: 256 rows x 128 B
#define BUFSTRIDE 65536     // A + B per buffer

typedef __attribute__((ext_vector_type(4))) int   i32x4;
typedef __attribute__((ext_vector_type(8))) int   i32x8;
typedef __attribute__((ext_vector_type(4))) float f32x4;

__device__ __forceinline__ void gload16(const void* g, void* l) {
    __builtin_amdgcn_global_load_lds(
        (const __attribute__((address_space(1))) void*)g,
        (__attribute__((address_space(3))) void*)l, 16, 0, 0);
}

__device__ __forceinline__ i32x8 pad8(i32x4 v) {
    i32x8 r;
    r[0] = v[0]; r[1] = v[1]; r[2] = v[2]; r[3] = v[3];
    r[4] = 0;    r[5] = 0;    r[6] = 0;    r[7] = 0;
    return r;
}

// scale 1.0 everywhere; fp4 format code = 4 for both operands.
#define MFMA_FP4(a, b, c)                                                   \
    __builtin_amdgcn_mfma_scale_f32_16x16x128_f8f6f4(                        \
        (a), (b), (c), 4, 4, 0, 0x7F7F7F7F, 0, 0x7F7F7F7F)

// ---------------- pack X -> A4 [M][K/2] fp4 nibbles (unchanged, BW-bound) ----
__global__ __launch_bounds__(256) void pack_a4_kernel(const float* __restrict__ X,
                                                      uint8_t* __restrict__ A4) {
    size_t gt = (size_t)blockIdx.x * 256 + threadIdx.x;
    const float4* x4 = (const float4*)X + gt * 4;
    uint32_t out[2] = {0, 0};
#pragma unroll
    for (int q = 0; q < 4; ++q) {
        float4 v = x4[q];
        uint32_t b0 = (v.x >= 0.f ? 0x2u : 0xAu) | ((v.y >= 0.f ? 0x2u : 0xAu) << 4);
        uint32_t b1 = (v.z >= 0.f ? 0x2u : 0xAu) | ((v.w >= 0.f ? 0x2u : 0xAu) << 4);
        out[q >> 1] |= (b0 | (b1 << 8)) << ((q & 1) * 16);
    }
    ((uint2*)A4)[gt] = make_uint2(out[0], out[1]);
}

// ---------------- pack W -> B4T [N][K/2] fp4 nibbles, transposed (unchanged) -
__global__ __launch_bounds__(256) void pack_b4t_kernel(const float* __restrict__ W,
                                                       uint8_t* __restrict__ B4) {
    __shared__ uint8_t t[64][72];                 // sign nibbles, +8 pad
    const int tid = threadIdx.x;
    const int k0 = blockIdx.y * 64, n0 = blockIdx.x * 64;
#pragma unroll
    for (int r = 0; r < 4; ++r) {
        int e  = r * 1024 + tid * 4;
        int k  = e >> 6;
        int nn = e & 63;
        float4 v = *(const float4*)&W[(size_t)(k0 + k) * NDIM + n0 + nn];
        uint32_t b0 = (v.x >= 0.f) ? 0x2u : 0xAu;
        uint32_t b1 = (v.y >= 0.f) ? 0x2u : 0xAu;
        uint32_t b2 = (v.z >= 0.f) ? 0x2u : 0xAu;
        uint32_t b3 = (v.w >= 0.f) ? 0x2u : 0xAu;
        *(uint32_t*)&t[k][nn] = b0 | (b1 << 8) | (b2 << 16) | (b3 << 24);
    }
    __syncthreads();
    const int n = tid >> 2, kc = tid & 3;         // 16 k-elems -> 8 bytes each
    uint32_t w[2] = {0, 0};
#pragma unroll
    for (int b = 0; b < 8; ++b) {
        int k = kc * 16 + b * 2;
        uint32_t byte = (uint32_t)t[k][n] | ((uint32_t)t[k + 1][n] << 4);
        w[b >> 2] |= byte << ((b & 3) * 8);
    }
    *(uint2*)&B4[(size_t)(n0 + n) * KB2 + k0 / 2 + kc * 8] = make_uint2(w[0], w[1]);
}

// ---------------- main: fp4 MFMA GEMM, 256x256 tile, pipelined ---------------
__global__ __launch_bounds__(512, 2) void binmm_fp4_kernel(const uint8_t* __restrict__ A4,
                                                           const uint8_t* __restrict__ B4,
                                                           float* __restrict__ C) {
    __shared__ uint8_t lds[2 * BUFSTRIDE];        // 128 KiB

    const int tid = threadIdx.x, lane = tid & 63, wid = tid >> 6;
    const int wr = wid >> 2, wc = wid & 3;        // 2x4 waves; wave tile 128x64
    const int l15 = lane & 15, g = (lane >> 4) & 3;
    const int m0 = blockIdx.y * BM, n0 = blockIdx.x * BN;

    // staging: per buffer, A = 256 rows x 8 slots x 16B (4 chunks of 64 rows),
    // same for B. Per thread: 4 A-loads + 4 B-loads of 16 B per K-tile.
    // LDS dest is linear tid*16 (wave base + lane*16, G21); source pre-swizzled.
    const int srow  = tid >> 3;                   // 0..63
    const int sslot = tid & 7;
    const uint8_t* gA[4];
    const uint8_t* gB[4];
#pragma unroll
    for (int p = 0; p < 4; ++p) {
        int row = srow + p * 64;
        int ss  = (sslot ^ (row & 7)) * 16;       // inverse-swizzled source slot
        gA[p] = A4 + (size_t)(m0 + row) * KB2 + ss;
        gB[p] = B4 + (size_t)(n0 + row) * KB2 + ss;
    }

    f32x4 acc[8][4];
#pragma unroll
    for (int m = 0; m < 8; ++m)
#pragma unroll
        for (int n = 0; n < 4; ++n) acc[m][n] = (f32x4){0.f, 0.f, 0.f, 0.f};

    // ---- prologue: stage tile 0 into buffer 0 ----
#pragma unroll
    for (int p = 0; p < 4; ++p) {
        gload16(gA[p], lds + tid * 16 + p * 8192);
        gload16(gB[p], lds + ABUF + tid * 16 + p * 8192);
        gA[p] += BKB;
        gB[p] += BKB;
    }
    __syncthreads();                              // drains vmcnt+lgkmcnt

    int cur = 0;
    for (int t = 0; t < NKT; ++t) {
        // ---- issue next tile's staging FIRST (in flight across MFMA phase) ----
        if (t + 1 < NKT) {
            uint8_t* nb = lds + (cur ^ 1) * BUFSTRIDE;
#pragma unroll
            for (int p = 0; p < 4; ++p) {
                gload16(gA[p], nb + tid * 16 + p * 8192);
                gload16(gB[p], nb + ABUF + tid * 16 + p * 8192);
                gA[p] += BKB;
                gB[p] += BKB;
            }
        }

        // ---- compute on current buffer ----
        const uint8_t* Acur = lds + cur * BUFSTRIDE;
        const uint8_t* Bcur = Acur + ABUF;
#pragma unroll
        for (int s = 0; s < 2; ++s) {             // two K=128 MFMA steps
            i32x8 bf[4];
#pragma unroll
            for (int n = 0; n < 4; ++n) {
                int row  = wc * 64 + n * 16 + l15;
                int slot = ((s * 4 + g) ^ (row & 7)) * 16;
                bf[n] = pad8(*(const i32x4*)(Bcur + row * 128 + slot));
            }
            __builtin_amdgcn_s_setprio(1);
#pragma unroll
            for (int m = 0; m < 8; ++m) {
                int row  = wr * 128 + m * 16 + l15;
                int slot = ((s * 4 + g) ^ (row & 7)) * 16;
                i32x8 af = pad8(*(const i32x4*)(Acur + row * 128 + slot));
                acc[m][0] = MFMA_FP4(af, bf[0], acc[m][0]);
                acc[m][1] = MFMA_FP4(af, bf[1], acc[m][1]);
                acc[m][2] = MFMA_FP4(af, bf[2], acc[m][2]);
                acc[m][3] = MFMA_FP4(af, bf[3], acc[m][3]);
            }
            __builtin_amdgcn_s_setprio(0);
        }

        // one barrier per K-tile: waits next-buf loads (issued ~2850 cyc ago)
        // and publishes "done reading cur" to all waves.
        __syncthreads();
        cur ^= 1;
    }

    // epilogue: C/D 16x16 layout: col = lane&15, row = (lane>>4)*4 + reg
#pragma unroll
    for (int m = 0; m < 8; ++m) {
#pragma unroll
        for (int n = 0; n < 4; ++n) {
            size_t cc = (size_t)(n0 + wc * 64 + n * 16 + l15);
            int rbase = m0 + wr * 128 + m * 16 + g * 4;
#pragma unroll
            for (int reg = 0; reg < 4; ++reg)
                C[(size_t)(rbase + reg) * NDIM + cc] = acc[m][n][reg];
        }
    }
}

// =============================================================================
extern "C" void kernel_launch(void* const* d_in, const int* in_sizes, int n_in,
                              void* d_out, int out_size, void* d_ws, size_t ws_size,
                              hipStream_t stream) {
    const float* x = (const float*)d_in[0];   // [8192][4096]
    const float* w = (const float*)d_in[1];   // [4096][4096]
    float* out = (float*)d_out;               // [8192][4096]

    // workspace: A4 [M][K/2] (16 MiB) then B4T [N][K/2] (8 MiB)
    uint8_t* A4 = (uint8_t*)d_ws;
    uint8_t* B4 = (uint8_t*)d_ws + (size_t)MDIM * KB2;

    pack_a4_kernel<<<(int)((size_t)MDIM * KDIM / 16 / 256), 256, 0, stream>>>(x, A4);
    pack_b4t_kernel<<<dim3(NDIM / 64, KDIM / 64), 256, 0, stream>>>(w, B4);
    binmm_fp4_kernel<<<dim3(NDIM / BN, MDIM / BM), 512, 0, stream>>>(A4, B4, out);
}

// Round 6
// 122.776 us; speedup vs baseline: 2.8001x; 1.0166x over previous
//
#include <hip/hip_runtime.h>
#include <stdint.h>

// C = binarize(X) @ binarize(W), exact via MX-fp4 (+-1) scaled MFMA.
// X: 8192x4096 f32, W: 4096x4096 f32, C: 8192x4096 f32.
// fp4 e2m1: +1.0 = 0x2, -1.0 = 0xA. Scale E8M0 127 = 1.0 (word 0x7F7F7F7F).
//
// R6: 256x256 tile, 8 waves (2x4), BK=256 fp4 (128 B/row), double-buffered
// LDS (128 KiB, 1 block/CU). NEW vs R5: per-K-tile 4-phase software pipeline
// (T3): reads for phase s+1 issued BEFORE the MFMA cluster of phase s via
// alternating fragment sets; staging for tile t+1 front-loaded in phases 0-1;
// mfma_scale_f32_32x32x64 (half the instructions, ~45cyc each -> better
// latency hiding); t-loop unrolled x2 for static buffer offsets.
// Swizzle carried from R4/R5 (verified conflict-free): phys_slot =
// logical_slot ^ (row&7); pre-swizzled GLOBAL source, linear gload_lds dest.
#define MDIM 8192
#define NDIM 4096
#define KDIM 4096
#define KB2  (KDIM / 2)     // 2048 B per packed row (2 fp4/byte)
#define BKB  128            // K-tile bytes = 256 fp4 elems
#define NKT  (KDIM / 256)   // 16 K-tiles

#define BM 256
#define BN 256
#define ABUF      32768     // A region per buffer: 256 rows x 128 B
#define BUFSTRIDE 65536     // A + B per buffer

typedef __attribute__((ext_vector_type(4)))  int   i32x4;
typedef __attribute__((ext_vector_type(8)))  int   i32x8;
typedef __attribute__((ext_vector_type(16))) float f32x16;

__device__ __forceinline__ void gload16(const void* g, void* l) {
    __builtin_amdgcn_global_load_lds(
        (const __attribute__((address_space(1))) void*)g,
        (__attribute__((address_space(3))) void*)l, 16, 0, 0);
}

__device__ __forceinline__ i32x8 pad8(i32x4 v) {
    i32x8 r;
    r[0] = v[0]; r[1] = v[1]; r[2] = v[2]; r[3] = v[3];
    r[4] = 0;    r[5] = 0;    r[6] = 0;    r[7] = 0;
    return r;
}

// scale 1.0 everywhere; fp4 format code = 4 for both operands.
#define MFMA_FP4_32(a, b, c)                                                 \
    __builtin_amdgcn_mfma_scale_f32_32x32x64_f8f6f4(                          \
        (a), (b), (c), 4, 4, 0, 0x7F7F7F7F, 0, 0x7F7F7F7F)

// ---------------- pack X -> A4 [M][K/2] fp4 nibbles (BW-bound) ---------------
__global__ __launch_bounds__(256) void pack_a4_kernel(const float* __restrict__ X,
                                                      uint8_t* __restrict__ A4) {
    size_t gt = (size_t)blockIdx.x * 256 + threadIdx.x;
    const float4* x4 = (const float4*)X + gt * 4;
    uint32_t out[2] = {0, 0};
#pragma unroll
    for (int q = 0; q < 4; ++q) {
        float4 v = x4[q];
        uint32_t b0 = (v.x >= 0.f ? 0x2u : 0xAu) | ((v.y >= 0.f ? 0x2u : 0xAu) << 4);
        uint32_t b1 = (v.z >= 0.f ? 0x2u : 0xAu) | ((v.w >= 0.f ? 0x2u : 0xAu) << 4);
        out[q >> 1] |= (b0 | (b1 << 8)) << ((q & 1) * 16);
    }
    ((uint2*)A4)[gt] = make_uint2(out[0], out[1]);
}

// ---------------- pack W -> B4T [N][K/2] fp4 nibbles, transposed -------------
__global__ __launch_bounds__(256) void pack_b4t_kernel(const float* __restrict__ W,
                                                       uint8_t* __restrict__ B4) {
    __shared__ uint8_t t[64][72];                 // sign nibbles, +8 pad
    const int tid = threadIdx.x;
    const int k0 = blockIdx.y * 64, n0 = blockIdx.x * 64;
#pragma unroll
    for (int r = 0; r < 4; ++r) {
        int e  = r * 1024 + tid * 4;
        int k  = e >> 6;
        int nn = e & 63;
        float4 v = *(const float4*)&W[(size_t)(k0 + k) * NDIM + n0 + nn];
        uint32_t b0 = (v.x >= 0.f) ? 0x2u : 0xAu;
        uint32_t b1 = (v.y >= 0.f) ? 0x2u : 0xAu;
        uint32_t b2 = (v.z >= 0.f) ? 0x2u : 0xAu;
        uint32_t b3 = (v.w >= 0.f) ? 0x2u : 0xAu;
        *(uint32_t*)&t[k][nn] = b0 | (b1 << 8) | (b2 << 16) | (b3 << 24);
    }
    __syncthreads();
    const int n = tid >> 2, kc = tid & 3;         // 16 k-elems -> 8 bytes each
    uint32_t w[2] = {0, 0};
#pragma unroll
    for (int b = 0; b < 8; ++b) {
        int k = kc * 16 + b * 2;
        uint32_t byte = (uint32_t)t[k][n] | ((uint32_t)t[k + 1][n] << 4);
        w[b >> 2] |= byte << ((b & 3) * 8);
    }
    *(uint2*)&B4[(size_t)(n0 + n) * KB2 + k0 / 2 + kc * 8] = make_uint2(w[0], w[1]);
}

// ---------------- main: fp4 MFMA GEMM, 256x256, 4-phase pipelined ------------
__global__ __launch_bounds__(512, 2) void binmm_fp4_kernel(const uint8_t* __restrict__ A4,
                                                           const uint8_t* __restrict__ B4,
                                                           float* __restrict__ C) {
    __shared__ uint8_t lds[2 * BUFSTRIDE];        // 128 KiB

    const int tid = threadIdx.x, lane = tid & 63, wid = tid >> 6;
    const int wr = wid >> 2, wc = wid & 3;        // 2x4 waves; wave tile 128x64
    const int l31 = lane & 31, kh = lane >> 5;    // 32x32 frag: row/col=l31
    const int m0 = blockIdx.y * BM, n0 = blockIdx.x * BN;

    // staging: rows tid>>3 (+p*64), slot tid&7; LDS dest linear (G21),
    // source slot pre-swizzled with ^(row&7).
    const int srow  = tid >> 3;
    const int sslot = tid & 7;
    const uint8_t* gA[4];
    const uint8_t* gB[4];
#pragma unroll
    for (int p = 0; p < 4; ++p) {
        int row = srow + p * 64;
        int ss  = (sslot ^ (row & 7)) * 16;
        gA[p] = A4 + (size_t)(m0 + row) * KB2 + ss;
        gB[p] = B4 + (size_t)(n0 + row) * KB2 + ss;
    }

    f32x16 acc[4][2];
#pragma unroll
    for (int m = 0; m < 4; ++m)
#pragma unroll
        for (int n = 0; n < 2; ++n)
#pragma unroll
            for (int e = 0; e < 16; ++e) acc[m][n][e] = 0.f;

    auto stageA = [&](int nxt) {
#pragma unroll
        for (int p = 0; p < 4; ++p) {
            gload16(gA[p], lds + nxt + tid * 16 + p * 8192);
            gA[p] += BKB;
        }
    };
    auto stageB = [&](int nxt) {
#pragma unroll
        for (int p = 0; p < 4; ++p) {
            gload16(gB[p], lds + nxt + ABUF + tid * 16 + p * 8192);
            gB[p] += BKB;
        }
    };

    // fragment reads for K-step s (64 elems = global slots s*2 + kh)
#define RDA(dst, cur, s) do {                                                  \
        _Pragma("unroll")                                                      \
        for (int mf = 0; mf < 4; ++mf) {                                       \
            int row = wr * 128 + mf * 32 + l31;                                \
            dst[mf] = *(const i32x4*)(lds + (cur) + row * 128 +                \
                                      ((((s) * 2 + kh) ^ (row & 7)) * 16));    \
        }                                                                      \
    } while (0)
#define RDB(dst, cur, s) do {                                                  \
        _Pragma("unroll")                                                      \
        for (int nf = 0; nf < 2; ++nf) {                                       \
            int row = wc * 64 + nf * 32 + l31;                                 \
            dst[nf] = *(const i32x4*)(lds + (cur) + ABUF + row * 128 +         \
                                      ((((s) * 2 + kh) ^ (row & 7)) * 16));    \
        }                                                                      \
    } while (0)
#define CLUSTER(AS, BS) do {                                                   \
        __builtin_amdgcn_s_setprio(1);                                         \
        _Pragma("unroll")                                                      \
        for (int mf = 0; mf < 4; ++mf) {                                       \
            i32x8 a8 = pad8(AS[mf]);                                           \
            acc[mf][0] = MFMA_FP4_32(a8, pad8(BS[0]), acc[mf][0]);             \
            acc[mf][1] = MFMA_FP4_32(a8, pad8(BS[1]), acc[mf][1]);             \
        }                                                                      \
        __builtin_amdgcn_s_setprio(0);                                         \
    } while (0)

    // one K-tile: 4 phases, reads pipelined one phase ahead, staging in ph0/ph1
    auto tile = [&](int cur, int nxt, bool do_stage) {
        i32x4 aP[4], bP[2], aQ[4], bQ[2];
        RDA(aP, cur, 0); RDB(bP, cur, 0);
        // phase 0
        if (do_stage) stageA(nxt);
        RDA(aQ, cur, 1); RDB(bQ, cur, 1);
        CLUSTER(aP, bP);
        // phase 1
        if (do_stage) stageB(nxt);
        RDA(aP, cur, 2); RDB(bP, cur, 2);
        CLUSTER(aQ, bQ);
        // phase 2
        RDA(aQ, cur, 3); RDB(bQ, cur, 3);
        CLUSTER(aP, bP);
        // phase 3
        CLUSTER(aQ, bQ);
        // barrier publishes cur free + waits nxt loads (issued >=2 phases ago)
        __syncthreads();
    };

    // prologue: stage tile 0 into buffer 0
    stageA(0); stageB(0);
    __syncthreads();

#pragma unroll 1
    for (int tt = 0; tt < NKT / 2 - 1; ++tt) {
        tile(0, BUFSTRIDE, true);
        tile(BUFSTRIDE, 0, true);
    }
    tile(0, BUFSTRIDE, true);
    tile(BUFSTRIDE, 0, false);

    // epilogue: C/D 32x32 layout: col = lane&31, row = (reg&3)+8*(reg>>2)+4*kh
#pragma unroll
    for (int mf = 0; mf < 4; ++mf) {
#pragma unroll
        for (int nf = 0; nf < 2; ++nf) {
            size_t cc = (size_t)(n0 + wc * 64 + nf * 32 + l31);
            int rbase = m0 + wr * 128 + mf * 32 + 4 * kh;
#pragma unroll
            for (int reg = 0; reg < 16; ++reg) {
                int rr = (reg & 3) + 8 * (reg >> 2);
                C[(size_t)(rbase + rr) * NDIM + cc] = acc[mf][nf][reg];
            }
        }
    }
}

// =============================================================================
extern "C" void kernel_launch(void* const* d_in, const int* in_sizes, int n_in,
                              void* d_out, int out_size, void* d_ws, size_t ws_size,
                              hipStream_t stream) {
    const float* x = (const float*)d_in[0];   // [8192][4096]
    const float* w = (const float*)d_in[1];   // [4096][4096]
    float* out = (float*)d_out;               // [8192][4096]

    // workspace: A4 [M][K/2] (16 MiB) then B4T [N][K/2] (8 MiB)
    uint8_t* A4 = (uint8_t*)d_ws;
    uint8_t* B4 = (uint8_t*)d_ws + (size_t)MDIM * KB2;

    pack_a4_kernel<<<(int)((size_t)MDIM * KDIM / 16 / 256), 256, 0, stream>>>(x, A4);
    pack_b4t_kernel<<<dim3(NDIM / 64, KDIM / 64), 256, 0, stream>>>(w, B4);
    binmm_fp4_kernel<<<dim3(NDIM / BN, MDIM / BM), 512, 0, stream>>>(A4, B4, out);
}